// Round 4
// baseline (79.034 us; speedup 1.0000x reference)
//
#include <hip/hip_runtime.h>

// SparseMaskedLinear: out[b,co] = bias[co] + sum_e in[b,ci_e]*w_e  (B=64, dims 2000)
// Dense reformulation: W[ci][co] = sum w_e;  out = in[:, :2000] @ W + bias.
// Pipeline: detect -> scatter (single-read, reg-resident, bin by ci>>3) ->
//           bin_build (8-row LDS tiles, exclusive) -> gemm (1024 blk) -> reduce.
// No global f32 atomics anywhere (measured ~20 G/s wall in round 1).

#define ROWS8 8
#define NB 256                 // hist slots (nbins <= 256)
#define BIN_CAP8 9216          // mean 8000, sigma ~89 -> 13.6 sigma headroom
#define E_PT 8
#define SEG3 (256 * E_PT)      // 2048 edges per scatter block

#define TILE_O 64
#define KS 64
#define SLICES 32
#define PSTRIDE 2048

// ---- int64-vs-int32 materialization detect (values < 2048 => int64 high words all 0)
__global__ void smw_detect(const unsigned int* __restrict__ m, int* __restrict__ flag) {
    if (blockIdx.x == 0 && threadIdx.x == 0) {
        unsigned int orv = 0u;
        for (int k = 0; k < 64; ++k) orv |= m[2 * k + 1];
        *flag = (orv == 0u) ? 1 : 0;   // 1 => int64 layout
    }
}

// ---- Phase 1: single-global-read scatter. 8 edges/thread held in registers
// (fully unrolled -> static indexing, no scratch). LDS-atomic rank during the
// load pass; one cursor atomicAdd per (bin,block) reserves the output range.
__global__ __launch_bounds__(256) void smw_scatter3(
    const int* __restrict__ mask, const float* __restrict__ wgt,
    const int* __restrict__ flag, int* __restrict__ cursor,
    int2* __restrict__ binned, int n_edges, int krows, int nbins) {
    __shared__ int hist[NB];
    __shared__ int sbase[NB];
    const int tid = threadIdx.x;
    const long long e0 = (long long)blockIdx.x * SEG3;
    if (tid < nbins) hist[tid] = 0;
    __syncthreads();
    const bool is64 = (*flag != 0);

    unsigned key[E_PT]; float wv[E_PT]; int pk[E_PT];  // pk = (bin<<16)|rank, -1 = skip
    #pragma unroll
    for (int i = 0; i < E_PT; ++i) {
        long long e = e0 + (long long)i * 256 + tid;
        pk[i] = -1; key[i] = 0u; wv[i] = 0.0f;
        if (e < n_edges) {
            int ci, co;
            if (is64) { int4 m = ((const int4*)mask)[e]; ci = m.x; co = m.z; }
            else      { int2 m = ((const int2*)mask)[e]; ci = m.x; co = m.y; }
            if ((unsigned)ci < (unsigned)krows) {
                int b = ci >> 3;                       // 8 rows per bin
                key[i] = ((unsigned)(ci & 7) << 16) | (unsigned)(co & 0xFFFF);
                wv[i]  = wgt[e];
                int r  = atomicAdd(&hist[b], 1);       // LDS rank
                pk[i]  = (b << 16) | r;                // r < 2048
            }
        }
    }
    __syncthreads();
    if (tid < nbins) {
        int c = hist[tid];
        sbase[tid] = c ? atomicAdd(&cursor[tid], c) : 0;  // one global int atomic per (bin,blk)
    }
    __syncthreads();
    #pragma unroll
    for (int i = 0; i < E_PT; ++i) {
        if (pk[i] >= 0) {
            int b   = pk[i] >> 16;
            int pos = sbase[b] + (pk[i] & 0xFFFF);
            if (pos < BIN_CAP8)
                binned[(long long)b * BIN_CAP8 + pos] =
                    make_int2((int)key[i], __float_as_int(wv[i]));
        }
    }
}

// ---- Phase 2: per-bin exclusive build of 8 W-rows in dynamic LDS, plain stores.
__global__ __launch_bounds__(512) void smw_bin_build3(
    const int2* __restrict__ binned, const int* __restrict__ cursor,
    float* __restrict__ W, int out_f, int krows) {
    extern __shared__ float tile[];                 // ROWS8 * out_f floats (<= 64 KB)
    const int tid = threadIdx.x;
    const int bin = blockIdx.x;
    const int tile_elems = ROWS8 * out_f;
    if ((out_f & 3) == 0) {
        float4* t4 = (float4*)tile;
        int n4 = tile_elems >> 2;
        for (int t = tid; t < n4; t += 512) t4[t] = make_float4(0.f, 0.f, 0.f, 0.f);
    } else {
        for (int t = tid; t < tile_elems; t += 512) tile[t] = 0.0f;
    }
    __syncthreads();
    int n = cursor[bin];
    if (n > BIN_CAP8) n = BIN_CAP8;
    const int2* src = binned + (long long)bin * BIN_CAP8;
    for (int i = tid; i < n; i += 512) {
        int2 rec = src[i];
        unsigned k = (unsigned)rec.x;
        atomicAdd(&tile[(int)(k >> 16) * out_f + (int)(k & 0xFFFFu)],
                  __int_as_float(rec.y));           // ds_add_f32, rows exclusive to block
    }
    __syncthreads();
    #pragma unroll
    for (int r = 0; r < ROWS8; ++r) {
        int row = bin * ROWS8 + r;
        if (row >= krows) break;
        float* dst = W + (long long)row * out_f;
        const float* s = tile + r * out_f;
        if ((out_f & 3) == 0) {
            for (int c = tid * 4; c < out_f; c += 2048)
                *(float4*)&dst[c] = *(const float4*)&s[c];
        } else {
            for (int c = tid; c < out_f; c += 512) dst[c] = s[c];
        }
    }
}

// ---- Phase 3: GEMM partial[s] = A[:, s*KS : s*KS+KS] @ W[slice, o_tile]
// 32 o-tiles x 32 slices = 1024 blocks, full slice staged once (float4), then
// 64 FMA iterations on a 4x4 register micro-tile. Plain float4 stores.
__global__ __launch_bounds__(256) void smw_gemm3(
    const float* __restrict__ A, const float* __restrict__ W,
    float* __restrict__ partial, int in_features, int out_f, int krows, int Bsz) {
    __shared__ float As[64][KS + 4];
    __shared__ float Ws[KS][TILE_O];
    const int tid = threadIdx.x;
    const int tx = tid & 15;
    const int ty = tid >> 4;
    const int o_base = blockIdx.x * TILE_O;
    const int k0 = blockIdx.y * KS;

    #pragma unroll
    for (int t = 0; t < 4; ++t) {
        int idx = t * 256 + tid;
        int b = idx >> 4;
        int c4 = (idx & 15) * 4;
        int gi = k0 + c4;
        float4 v = make_float4(0.f, 0.f, 0.f, 0.f);
        if (b < Bsz) {
            const float* src = A + (long long)b * in_features + gi;
            if (gi + 3 < krows) v = *(const float4*)src;
            else {
                if (gi + 0 < krows) v.x = src[0];
                if (gi + 1 < krows) v.y = src[1];
                if (gi + 2 < krows) v.z = src[2];
                if (gi + 3 < krows) v.w = src[3];
            }
        }
        *(float4*)&As[b][c4] = v;
    }
    #pragma unroll
    for (int t = 0; t < 4; ++t) {
        int idx = t * 256 + tid;
        int r = idx >> 4;
        int c4 = (idx & 15) * 4;
        int gi = k0 + r;
        int go = o_base + c4;
        float4 v = make_float4(0.f, 0.f, 0.f, 0.f);
        if (gi < krows) {
            const float* src = W + (long long)gi * out_f + go;
            if (go + 3 < out_f) v = *(const float4*)src;
            else {
                if (go + 0 < out_f) v.x = src[0];
                if (go + 1 < out_f) v.y = src[1];
                if (go + 2 < out_f) v.z = src[2];
                if (go + 3 < out_f) v.w = src[3];
            }
        }
        *(float4*)&Ws[r][c4] = v;
    }
    __syncthreads();

    float acc[4][4] = {};
    #pragma unroll 8
    for (int i = 0; i < KS; ++i) {
        float4 w4 = *(const float4*)&Ws[i][tx * 4];
        float a[4];
        #pragma unroll
        for (int r = 0; r < 4; ++r) a[r] = As[ty * 4 + r][i];
        #pragma unroll
        for (int r = 0; r < 4; ++r) {
            acc[r][0] += a[r] * w4.x;
            acc[r][1] += a[r] * w4.y;
            acc[r][2] += a[r] * w4.z;
            acc[r][3] += a[r] * w4.w;
        }
    }

    float* P = partial + (long long)blockIdx.y * 64 * PSTRIDE;
    #pragma unroll
    for (int r = 0; r < 4; ++r) {
        int b = ty * 4 + r;
        if (b < Bsz)
            *(float4*)&P[(long long)b * PSTRIDE + o_base + tx * 4] =
                make_float4(acc[r][0], acc[r][1], acc[r][2], acc[r][3]);
    }
}

// ---- Phase 4: out = bias + sum_s partial[s]
__global__ void smw_reduce2(const float* __restrict__ partial,
                            const float* __restrict__ bias,
                            float* __restrict__ out, int out_f, int Bsz, int total) {
    int idx = blockIdx.x * blockDim.x + threadIdx.x;
    if (idx >= total) return;
    int b = idx / out_f, o = idx - b * out_f;
    float acc = bias[o];
    #pragma unroll
    for (int s = 0; s < SLICES; ++s)
        acc += partial[((long long)s * 64 + b) * PSTRIDE + o];
    out[idx] = acc;
}

// ================= fallback path (round-1, known-good, needs only 16 MB ws) ==
__global__ void smw_build_fb(const int* __restrict__ mask, const float* __restrict__ wgt,
                             float* __restrict__ W, const int* __restrict__ flag,
                             int n_edges, int out_f) {
    int e = blockIdx.x * blockDim.x + threadIdx.x;
    if (e >= n_edges) return;
    int ci, co;
    if (*flag) {
        const long long* m64 = (const long long*)mask;
        ci = (int)m64[2 * (long long)e];
        co = (int)m64[2 * (long long)e + 1];
    } else {
        ci = mask[2 * e]; co = mask[2 * e + 1];
    }
    atomicAdd(&W[(long long)ci * out_f + co], wgt[e]);
}

__global__ void smw_init_out_fb(float* __restrict__ out, const float* __restrict__ bias,
                                int total, int out_f) {
    int idx = blockIdx.x * blockDim.x + threadIdx.x;
    if (idx < total) out[idx] = bias[idx % out_f];
}

__global__ __launch_bounds__(256) void smw_gemm_fb(
    const float* __restrict__ A, const float* __restrict__ W,
    float* __restrict__ out, int in_features, int out_f, int krows,
    int n_chunks, int Bsz) {
    __shared__ float As[64][36];
    __shared__ float Ws[32][64];
    const int tid = threadIdx.x;
    const int tx = tid & 15;
    const int ty = tid >> 4;
    const int o_base = blockIdx.x * 64;
    float acc[4][4] = {};
    for (int c = blockIdx.y; c < n_chunks; c += 8) {
        const int i0 = c * 32;
        __syncthreads();
        #pragma unroll
        for (int k = 0; k < 8; ++k) {
            int idx = k * 256 + tid;
            int i = idx & 31;
            int b = idx >> 5;
            float v = 0.0f;
            int gi = i0 + i;
            if (b < Bsz && gi < in_features) v = A[(long long)b * in_features + gi];
            As[b][i] = v;
        }
        #pragma unroll
        for (int k = 0; k < 8; ++k) {
            int idx = k * 256 + tid;
            int o = idx & 63;
            int i = idx >> 6;
            int gi = i0 + i;
            int go = o_base + o;
            Ws[i][o] = (gi < krows && go < out_f) ? W[(long long)gi * out_f + go] : 0.0f;
        }
        __syncthreads();
        #pragma unroll
        for (int i = 0; i < 32; ++i) {
            float4 w4 = *(const float4*)(&Ws[i][tx * 4]);
            float a[4];
            #pragma unroll
            for (int r = 0; r < 4; ++r) a[r] = As[ty * 4 + r][i];
            #pragma unroll
            for (int r = 0; r < 4; ++r) {
                acc[r][0] += a[r] * w4.x;
                acc[r][1] += a[r] * w4.y;
                acc[r][2] += a[r] * w4.z;
                acc[r][3] += a[r] * w4.w;
            }
        }
    }
    #pragma unroll
    for (int r = 0; r < 4; ++r) {
        int b = ty * 4 + r;
        if (b >= Bsz) continue;
        #pragma unroll
        for (int cc = 0; cc < 4; ++cc) {
            int o = o_base + tx * 4 + cc;
            if (o < out_f) atomicAdd(&out[(long long)b * out_f + o], acc[r][cc]);
        }
    }
}

// =============================================================================
static inline size_t align_up(size_t x, size_t a) { return (x + a - 1) & ~(a - 1); }

extern "C" void kernel_launch(void* const* d_in, const int* in_sizes, int n_in,
                              void* d_out, int out_size, void* d_ws, size_t ws_size,
                              hipStream_t stream) {
    const float* input = (const float*)d_in[0];
    const int*   mask  = (const int*)d_in[1];
    const float* wgt   = (const float*)d_in[2];
    const float* bias  = (const float*)d_in[3];
    float* out = (float*)d_out;

    const int out_f   = in_sizes[3];            // 2000
    const int n_edges = in_sizes[2];            // 2,000,000
    const int Bsz     = out_size / out_f;       // 64
    const int in_features = in_sizes[0] / Bsz;  // 20000
    const int krows   = out_f;                  // ci values < out_f per problem spec
    const int nbins   = (krows + ROWS8 - 1) / ROWS8;   // 250

    size_t W_bytes      = align_up((size_t)krows * out_f * 4, 1024);
    size_t binned_bytes = align_up((size_t)nbins * BIN_CAP8 * 8, 1024);   // 18.4 MB
    size_t part_bytes   = align_up((size_t)SLICES * 64 * PSTRIDE * 4, 1024);
    size_t union_bytes  = binned_bytes > part_bytes ? binned_bytes : part_bytes;
    size_t meta_bytes   = 4096;
    size_t need_fast = W_bytes + union_bytes + meta_bytes;   // ~34.8 MB

    char* p = (char*)d_ws;
    float* W      = (float*)p;
    int2*  binned = (int2*)(p + W_bytes);         // dead after bin_build
    float* partial= (float*)(p + W_bytes);        // same region, used after
    int*   cursor = (int*)(p + W_bytes + union_bytes);
    int*   flag   = cursor + NB;

    const size_t lds_bytes = (size_t)ROWS8 * out_f * 4;   // <= 64 KB when out_f <= 2048
    const bool fast = (ws_size >= need_fast) && out_f <= 2048 && krows <= 2048 &&
                      nbins <= NB && Bsz <= 64 && n_edges >= 1 && lds_bytes <= 65536;

    if (fast) {
        hipMemsetAsync(cursor, 0, nbins * sizeof(int), stream);
        smw_detect<<<1, 64, 0, stream>>>((const unsigned int*)mask, flag);
        int nseg = (n_edges + SEG3 - 1) / SEG3;                   // 977
        smw_scatter3<<<nseg, 256, 0, stream>>>(mask, wgt, flag, cursor, binned,
                                               n_edges, krows, nbins);
        smw_bin_build3<<<nbins, 512, lds_bytes, stream>>>(binned, cursor, W, out_f, krows);
        dim3 grid((out_f + TILE_O - 1) / TILE_O, SLICES);         // 32 x 32
        smw_gemm3<<<grid, 256, 0, stream>>>(input, W, partial, in_features, out_f,
                                            krows, Bsz);
        smw_reduce2<<<(out_size + 255) / 256, 256, 0, stream>>>(partial, bias, out,
                                                                out_f, Bsz, out_size);
    } else {
        // round-1 known-good path (16 MB + flag)
        int* flag_fb = (int*)(p + (size_t)krows * out_f * 4);
        hipMemsetAsync(d_ws, 0, (size_t)krows * out_f * 4, stream);
        smw_detect<<<1, 64, 0, stream>>>((const unsigned int*)mask, flag_fb);
        smw_build_fb<<<(n_edges + 255) / 256, 256, 0, stream>>>(mask, wgt, W, flag_fb,
                                                                n_edges, out_f);
        smw_init_out_fb<<<(out_size + 255) / 256, 256, 0, stream>>>(out, bias, out_size, out_f);
        const int n_chunks = (krows + 31) / 32;
        dim3 grid((out_f + 63) / 64, 8);
        smw_gemm_fb<<<grid, 256, 0, stream>>>(input, W, out, in_features, out_f,
                                              krows, n_chunks, Bsz);
    }
}

// Round 5
// 69.928 us; speedup vs baseline: 1.1302x; 1.1302x over previous
//
#include <hip/hip_runtime.h>

// SparseMaskedLinear: out[b,co] = bias[co] + sum_e in[b,ci_e]*w_e  (B=64, dims 2000)
// Dense reformulation: W[ci][co] = sum w_e;  out = in[:, :2000] @ W + bias.
// Pipeline: detect -> scatter (single-read, bin by ci>>3) -> bin_build (8-row
// LDS tiles, exclusive) -> gemm (1024 blk) -> reduce.
// Round-5 change: cursor counters padded to 1 per 128 B. 244K global atomics
// previously hit ~16 cache lines -> per-line serialized RMW chains (~30 us).
// Padding gives each bin its own line; chains run parallel across L2 banks.

#define ROWS8 8
#define NB 256                 // hist slots (nbins <= 256)
#define CUR_STRIDE 32          // one cursor per 128 B line
#define BIN_CAP8 9216          // mean 8000, sigma ~89 -> 13.6 sigma headroom
#define E_PT 8
#define SEG3 (256 * E_PT)      // 2048 edges per scatter block

#define TILE_O 64
#define KS 64
#define SLICES 32
#define PSTRIDE 2048

// ---- int64-vs-int32 materialization detect (values < 2048 => int64 high words all 0)
__global__ void smw_detect(const unsigned int* __restrict__ m, int* __restrict__ flag) {
    if (blockIdx.x == 0 && threadIdx.x == 0) {
        unsigned int orv = 0u;
        for (int k = 0; k < 64; ++k) orv |= m[2 * k + 1];
        *flag = (orv == 0u) ? 1 : 0;   // 1 => int64 layout
    }
}

// ---- Phase 1: single-global-read scatter. 8 edges/thread held in registers
// (fully unrolled -> static indexing). LDS-atomic rank during the load pass;
// one PADDED cursor atomicAdd per (bin,block) reserves the output range.
__global__ __launch_bounds__(256) void smw_scatter3(
    const int* __restrict__ mask, const float* __restrict__ wgt,
    const int* __restrict__ flag, int* __restrict__ cursor,
    int2* __restrict__ binned, int n_edges, int krows, int nbins) {
    __shared__ int hist[NB];
    __shared__ int sbase[NB];
    const int tid = threadIdx.x;
    const long long e0 = (long long)blockIdx.x * SEG3;
    if (tid < nbins) hist[tid] = 0;
    __syncthreads();
    const bool is64 = (*flag != 0);

    unsigned key[E_PT]; float wv[E_PT]; int pk[E_PT];  // pk = (bin<<16)|rank, -1 = skip
    #pragma unroll
    for (int i = 0; i < E_PT; ++i) {
        long long e = e0 + (long long)i * 256 + tid;
        pk[i] = -1; key[i] = 0u; wv[i] = 0.0f;
        if (e < n_edges) {
            int ci, co;
            if (is64) { int4 m = ((const int4*)mask)[e]; ci = m.x; co = m.z; }
            else      { int2 m = ((const int2*)mask)[e]; ci = m.x; co = m.y; }
            if ((unsigned)ci < (unsigned)krows) {
                int b = ci >> 3;                       // 8 rows per bin
                key[i] = ((unsigned)(ci & 7) << 16) | (unsigned)(co & 0xFFFF);
                wv[i]  = wgt[e];
                int r  = atomicAdd(&hist[b], 1);       // LDS rank
                pk[i]  = (b << 16) | r;                // r < 2048
            }
        }
    }
    __syncthreads();
    if (tid < nbins) {
        int c = hist[tid];
        sbase[tid] = c ? atomicAdd(&cursor[tid * CUR_STRIDE], c) : 0;  // own line per bin
    }
    __syncthreads();
    #pragma unroll
    for (int i = 0; i < E_PT; ++i) {
        if (pk[i] >= 0) {
            int b   = pk[i] >> 16;
            int pos = sbase[b] + (pk[i] & 0xFFFF);
            if (pos < BIN_CAP8)
                binned[(long long)b * BIN_CAP8 + pos] =
                    make_int2((int)key[i], __float_as_int(wv[i]));
        }
    }
}

// ---- Phase 2: per-bin exclusive build of 8 W-rows in dynamic LDS, plain stores.
__global__ __launch_bounds__(512) void smw_bin_build3(
    const int2* __restrict__ binned, const int* __restrict__ cursor,
    float* __restrict__ W, int out_f, int krows) {
    extern __shared__ float tile[];                 // ROWS8 * out_f floats (<= 64 KB)
    const int tid = threadIdx.x;
    const int bin = blockIdx.x;
    const int tile_elems = ROWS8 * out_f;
    if ((out_f & 3) == 0) {
        float4* t4 = (float4*)tile;
        int n4 = tile_elems >> 2;
        for (int t = tid; t < n4; t += 512) t4[t] = make_float4(0.f, 0.f, 0.f, 0.f);
    } else {
        for (int t = tid; t < tile_elems; t += 512) tile[t] = 0.0f;
    }
    __syncthreads();
    int n = cursor[bin * CUR_STRIDE];
    if (n > BIN_CAP8) n = BIN_CAP8;
    const int2* src = binned + (long long)bin * BIN_CAP8;
    for (int i = tid; i < n; i += 512) {
        int2 rec = src[i];
        unsigned k = (unsigned)rec.x;
        atomicAdd(&tile[(int)(k >> 16) * out_f + (int)(k & 0xFFFFu)],
                  __int_as_float(rec.y));           // ds_add_f32, rows exclusive to block
    }
    __syncthreads();
    #pragma unroll
    for (int r = 0; r < ROWS8; ++r) {
        int row = bin * ROWS8 + r;
        if (row >= krows) break;
        float* dst = W + (long long)row * out_f;
        const float* s = tile + r * out_f;
        if ((out_f & 3) == 0) {
            for (int c = tid * 4; c < out_f; c += 2048)
                *(float4*)&dst[c] = *(const float4*)&s[c];
        } else {
            for (int c = tid; c < out_f; c += 512) dst[c] = s[c];
        }
    }
}

// ---- Phase 3: GEMM partial[s] = A[:, s*KS : s*KS+KS] @ W[slice, o_tile]
// 32 o-tiles x 32 slices = 1024 blocks, full slice staged once (float4), then
// 64 FMA iterations on a 4x4 register micro-tile. Plain float4 stores.
__global__ __launch_bounds__(256) void smw_gemm3(
    const float* __restrict__ A, const float* __restrict__ W,
    float* __restrict__ partial, int in_features, int out_f, int krows, int Bsz) {
    __shared__ float As[64][KS + 4];
    __shared__ float Ws[KS][TILE_O];
    const int tid = threadIdx.x;
    const int tx = tid & 15;
    const int ty = tid >> 4;
    const int o_base = blockIdx.x * TILE_O;
    const int k0 = blockIdx.y * KS;

    #pragma unroll
    for (int t = 0; t < 4; ++t) {
        int idx = t * 256 + tid;
        int b = idx >> 4;
        int c4 = (idx & 15) * 4;
        int gi = k0 + c4;
        float4 v = make_float4(0.f, 0.f, 0.f, 0.f);
        if (b < Bsz) {
            const float* src = A + (long long)b * in_features + gi;
            if (gi + 3 < krows) v = *(const float4*)src;
            else {
                if (gi + 0 < krows) v.x = src[0];
                if (gi + 1 < krows) v.y = src[1];
                if (gi + 2 < krows) v.z = src[2];
                if (gi + 3 < krows) v.w = src[3];
            }
        }
        *(float4*)&As[b][c4] = v;
    }
    #pragma unroll
    for (int t = 0; t < 4; ++t) {
        int idx = t * 256 + tid;
        int r = idx >> 4;
        int c4 = (idx & 15) * 4;
        int gi = k0 + r;
        int go = o_base + c4;
        float4 v = make_float4(0.f, 0.f, 0.f, 0.f);
        if (gi < krows) {
            const float* src = W + (long long)gi * out_f + go;
            if (go + 3 < out_f) v = *(const float4*)src;
            else {
                if (go + 0 < out_f) v.x = src[0];
                if (go + 1 < out_f) v.y = src[1];
                if (go + 2 < out_f) v.z = src[2];
                if (go + 3 < out_f) v.w = src[3];
            }
        }
        *(float4*)&Ws[r][c4] = v;
    }
    __syncthreads();

    float acc[4][4] = {};
    #pragma unroll 8
    for (int i = 0; i < KS; ++i) {
        float4 w4 = *(const float4*)&Ws[i][tx * 4];
        float a[4];
        #pragma unroll
        for (int r = 0; r < 4; ++r) a[r] = As[ty * 4 + r][i];
        #pragma unroll
        for (int r = 0; r < 4; ++r) {
            acc[r][0] += a[r] * w4.x;
            acc[r][1] += a[r] * w4.y;
            acc[r][2] += a[r] * w4.z;
            acc[r][3] += a[r] * w4.w;
        }
    }

    float* P = partial + (long long)blockIdx.y * 64 * PSTRIDE;
    #pragma unroll
    for (int r = 0; r < 4; ++r) {
        int b = ty * 4 + r;
        if (b < Bsz)
            *(float4*)&P[(long long)b * PSTRIDE + o_base + tx * 4] =
                make_float4(acc[r][0], acc[r][1], acc[r][2], acc[r][3]);
    }
}

// ---- Phase 4: out = bias + sum_s partial[s]
__global__ void smw_reduce2(const float* __restrict__ partial,
                            const float* __restrict__ bias,
                            float* __restrict__ out, int out_f, int Bsz, int total) {
    int idx = blockIdx.x * blockDim.x + threadIdx.x;
    if (idx >= total) return;
    int b = idx / out_f, o = idx - b * out_f;
    float acc = bias[o];
    #pragma unroll
    for (int s = 0; s < SLICES; ++s)
        acc += partial[((long long)s * 64 + b) * PSTRIDE + o];
    out[idx] = acc;
}

// ================= fallback path (round-1, known-good, needs only 16 MB ws) ==
__global__ void smw_build_fb(const int* __restrict__ mask, const float* __restrict__ wgt,
                             float* __restrict__ W, const int* __restrict__ flag,
                             int n_edges, int out_f) {
    int e = blockIdx.x * blockDim.x + threadIdx.x;
    if (e >= n_edges) return;
    int ci, co;
    if (*flag) {
        const long long* m64 = (const long long*)mask;
        ci = (int)m64[2 * (long long)e];
        co = (int)m64[2 * (long long)e + 1];
    } else {
        ci = mask[2 * e]; co = mask[2 * e + 1];
    }
    atomicAdd(&W[(long long)ci * out_f + co], wgt[e]);
}

__global__ void smw_init_out_fb(float* __restrict__ out, const float* __restrict__ bias,
                                int total, int out_f) {
    int idx = blockIdx.x * blockDim.x + threadIdx.x;
    if (idx < total) out[idx] = bias[idx % out_f];
}

__global__ __launch_bounds__(256) void smw_gemm_fb(
    const float* __restrict__ A, const float* __restrict__ W,
    float* __restrict__ out, int in_features, int out_f, int krows,
    int n_chunks, int Bsz) {
    __shared__ float As[64][36];
    __shared__ float Ws[32][64];
    const int tid = threadIdx.x;
    const int tx = tid & 15;
    const int ty = tid >> 4;
    const int o_base = blockIdx.x * 64;
    float acc[4][4] = {};
    for (int c = blockIdx.y; c < n_chunks; c += 8) {
        const int i0 = c * 32;
        __syncthreads();
        #pragma unroll
        for (int k = 0; k < 8; ++k) {
            int idx = k * 256 + tid;
            int i = idx & 31;
            int b = idx >> 5;
            float v = 0.0f;
            int gi = i0 + i;
            if (b < Bsz && gi < in_features) v = A[(long long)b * in_features + gi];
            As[b][i] = v;
        }
        #pragma unroll
        for (int k = 0; k < 8; ++k) {
            int idx = k * 256 + tid;
            int o = idx & 63;
            int i = idx >> 6;
            int gi = i0 + i;
            int go = o_base + o;
            Ws[i][o] = (gi < krows && go < out_f) ? W[(long long)gi * out_f + go] : 0.0f;
        }
        __syncthreads();
        #pragma unroll
        for (int i = 0; i < 32; ++i) {
            float4 w4 = *(const float4*)(&Ws[i][tx * 4]);
            float a[4];
            #pragma unroll
            for (int r = 0; r < 4; ++r) a[r] = As[ty * 4 + r][i];
            #pragma unroll
            for (int r = 0; r < 4; ++r) {
                acc[r][0] += a[r] * w4.x;
                acc[r][1] += a[r] * w4.y;
                acc[r][2] += a[r] * w4.z;
                acc[r][3] += a[r] * w4.w;
            }
        }
    }
    #pragma unroll
    for (int r = 0; r < 4; ++r) {
        int b = ty * 4 + r;
        if (b >= Bsz) continue;
        #pragma unroll
        for (int cc = 0; cc < 4; ++cc) {
            int o = o_base + tx * 4 + cc;
            if (o < out_f) atomicAdd(&out[(long long)b * out_f + o], acc[r][cc]);
        }
    }
}

// =============================================================================
static inline size_t align_up(size_t x, size_t a) { return (x + a - 1) & ~(a - 1); }

extern "C" void kernel_launch(void* const* d_in, const int* in_sizes, int n_in,
                              void* d_out, int out_size, void* d_ws, size_t ws_size,
                              hipStream_t stream) {
    const float* input = (const float*)d_in[0];
    const int*   mask  = (const int*)d_in[1];
    const float* wgt   = (const float*)d_in[2];
    const float* bias  = (const float*)d_in[3];
    float* out = (float*)d_out;

    const int out_f   = in_sizes[3];            // 2000
    const int n_edges = in_sizes[2];            // 2,000,000
    const int Bsz     = out_size / out_f;       // 64
    const int in_features = in_sizes[0] / Bsz;  // 20000
    const int krows   = out_f;                  // ci values < out_f per problem spec
    const int nbins   = (krows + ROWS8 - 1) / ROWS8;   // 250

    size_t W_bytes      = align_up((size_t)krows * out_f * 4, 1024);
    size_t binned_bytes = align_up((size_t)nbins * BIN_CAP8 * 8, 1024);   // 18.4 MB
    size_t part_bytes   = align_up((size_t)SLICES * 64 * PSTRIDE * 4, 1024);
    size_t union_bytes  = binned_bytes > part_bytes ? binned_bytes : part_bytes;
    size_t cursor_bytes = (size_t)NB * CUR_STRIDE * 4;   // 32 KB padded cursors
    size_t meta_bytes   = cursor_bytes + 4096;
    size_t need_fast = W_bytes + union_bytes + meta_bytes;   // ~34.9 MB

    char* p = (char*)d_ws;
    float* W      = (float*)p;
    int2*  binned = (int2*)(p + W_bytes);         // dead after bin_build
    float* partial= (float*)(p + W_bytes);        // same region, used after
    int*   cursor = (int*)(p + W_bytes + union_bytes);
    int*   flag   = (int*)(p + W_bytes + union_bytes + cursor_bytes);

    const size_t lds_bytes = (size_t)ROWS8 * out_f * 4;   // <= 64 KB when out_f <= 2048
    const bool fast = (ws_size >= need_fast) && out_f <= 2048 && krows <= 2048 &&
                      nbins <= NB && Bsz <= 64 && n_edges >= 1 && lds_bytes <= 65536;

    if (fast) {
        hipMemsetAsync(cursor, 0, cursor_bytes, stream);
        smw_detect<<<1, 64, 0, stream>>>((const unsigned int*)mask, flag);
        int nseg = (n_edges + SEG3 - 1) / SEG3;                   // 977
        smw_scatter3<<<nseg, 256, 0, stream>>>(mask, wgt, flag, cursor, binned,
                                               n_edges, krows, nbins);
        smw_bin_build3<<<nbins, 512, lds_bytes, stream>>>(binned, cursor, W, out_f, krows);
        dim3 grid((out_f + TILE_O - 1) / TILE_O, SLICES);         // 32 x 32
        smw_gemm3<<<grid, 256, 0, stream>>>(input, W, partial, in_features, out_f,
                                            krows, Bsz);
        smw_reduce2<<<(out_size + 255) / 256, 256, 0, stream>>>(partial, bias, out,
                                                                out_f, Bsz, out_size);
    } else {
        // round-1 known-good path (16 MB + flag)
        int* flag_fb = (int*)(p + (size_t)krows * out_f * 4);
        hipMemsetAsync(d_ws, 0, (size_t)krows * out_f * 4, stream);
        smw_detect<<<1, 64, 0, stream>>>((const unsigned int*)mask, flag_fb);
        smw_build_fb<<<(n_edges + 255) / 256, 256, 0, stream>>>(mask, wgt, W, flag_fb,
                                                                n_edges, out_f);
        smw_init_out_fb<<<(out_size + 255) / 256, 256, 0, stream>>>(out, bias, out_size, out_f);
        const int n_chunks = (krows + 31) / 32;
        dim3 grid((out_f + 63) / 64, 8);
        smw_gemm_fb<<<grid, 256, 0, stream>>>(input, W, out, in_features, out_f,
                                              krows, n_chunks, Bsz);
    }
}

// Round 6
// 68.520 us; speedup vs baseline: 1.1535x; 1.0206x over previous
//
#include <hip/hip_runtime.h>

// SparseMaskedLinear: out[b,co] = bias[co] + sum_e in[b,ci_e]*w_e  (B=64, dims 2000)
// Dense reformulation: W[ci][co] = sum w_e;  out = in[:, :2000] @ W + bias.
// Pipeline: detect -> scatter (245 fat blocks, bin by ci>>3, padded cursors) ->
//           bin_build (8-row LDS tiles, exclusive) -> gemm (2-chunk K) -> reduce.
// Round-6: scatter blocks 977->245 (cursor RMW chain per line /4), SLICES 32->16
// (partial traffic halved), float4 reduce.

#define ROWS8 8
#define NB 256                 // hist slots (nbins <= 256)
#define CUR_STRIDE 32          // one cursor per 128 B line
#define BIN_CAP8 9216          // mean 8000, sigma ~89 -> 13.6 sigma headroom
#define E_PT 8
#define TPB_SC 1024
#define SEG4 (TPB_SC * E_PT)   // 8192 edges per scatter block

#define TILE_O 64
#define KS 64
#define SLICES 16              // 16 partial slices, 2 K-chunks of 64 each
#define PSTRIDE 2048

// ---- int64-vs-int32 materialization detect (values < 2048 => int64 high words all 0)
__global__ void smw_detect(const unsigned int* __restrict__ m, int* __restrict__ flag) {
    if (blockIdx.x == 0 && threadIdx.x == 0) {
        unsigned int orv = 0u;
        for (int k = 0; k < 64; ++k) orv |= m[2 * k + 1];
        *flag = (orv == 0u) ? 1 : 0;   // 1 => int64 layout
    }
}

// ---- Phase 1: single-global-read scatter. 1024 threads x 8 edges in registers
// (fully unrolled -> static indexing). LDS-atomic rank during the load pass;
// one padded-cursor atomicAdd per (bin,block) reserves the output range.
__global__ __launch_bounds__(1024) void smw_scatter4(
    const int* __restrict__ mask, const float* __restrict__ wgt,
    const int* __restrict__ flag, int* __restrict__ cursor,
    int2* __restrict__ binned, int n_edges, int krows, int nbins) {
    __shared__ int hist[NB];
    __shared__ int sbase[NB];
    const int tid = threadIdx.x;
    const long long e0 = (long long)blockIdx.x * SEG4;
    if (tid < nbins) hist[tid] = 0;
    __syncthreads();
    const bool is64 = (*flag != 0);

    unsigned key[E_PT]; float wv[E_PT]; int pk[E_PT];  // pk = (bin<<16)|rank, -1 = skip
    #pragma unroll
    for (int i = 0; i < E_PT; ++i) {
        long long e = e0 + (long long)i * TPB_SC + tid;
        pk[i] = -1; key[i] = 0u; wv[i] = 0.0f;
        if (e < n_edges) {
            int ci, co;
            if (is64) { int4 m = ((const int4*)mask)[e]; ci = m.x; co = m.z; }
            else      { int2 m = ((const int2*)mask)[e]; ci = m.x; co = m.y; }
            if ((unsigned)ci < (unsigned)krows) {
                int b = ci >> 3;                       // 8 rows per bin
                key[i] = ((unsigned)(ci & 7) << 16) | (unsigned)(co & 0xFFFF);
                wv[i]  = wgt[e];
                int r  = atomicAdd(&hist[b], 1);       // LDS rank, r < 8192
                pk[i]  = (b << 16) | r;
            }
        }
    }
    __syncthreads();
    if (tid < nbins) {
        int c = hist[tid];
        sbase[tid] = c ? atomicAdd(&cursor[tid * CUR_STRIDE], c) : 0;  // own line per bin
    }
    __syncthreads();
    #pragma unroll
    for (int i = 0; i < E_PT; ++i) {
        if (pk[i] >= 0) {
            int b   = pk[i] >> 16;
            int pos = sbase[b] + (pk[i] & 0xFFFF);
            if (pos < BIN_CAP8)
                binned[(long long)b * BIN_CAP8 + pos] =
                    make_int2((int)key[i], __float_as_int(wv[i]));
        }
    }
}

// ---- Phase 2: per-bin exclusive build of 8 W-rows in dynamic LDS, plain stores.
__global__ __launch_bounds__(512) void smw_bin_build3(
    const int2* __restrict__ binned, const int* __restrict__ cursor,
    float* __restrict__ W, int out_f, int krows) {
    extern __shared__ float tile[];                 // ROWS8 * out_f floats (<= 64 KB)
    const int tid = threadIdx.x;
    const int bin = blockIdx.x;
    const int tile_elems = ROWS8 * out_f;
    if ((out_f & 3) == 0) {
        float4* t4 = (float4*)tile;
        int n4 = tile_elems >> 2;
        for (int t = tid; t < n4; t += 512) t4[t] = make_float4(0.f, 0.f, 0.f, 0.f);
    } else {
        for (int t = tid; t < tile_elems; t += 512) tile[t] = 0.0f;
    }
    __syncthreads();
    int n = cursor[bin * CUR_STRIDE];
    if (n > BIN_CAP8) n = BIN_CAP8;
    const int2* src = binned + (long long)bin * BIN_CAP8;
    for (int i = tid; i < n; i += 512) {
        int2 rec = src[i];
        unsigned k = (unsigned)rec.x;
        atomicAdd(&tile[(int)(k >> 16) * out_f + (int)(k & 0xFFFFu)],
                  __int_as_float(rec.y));           // ds_add_f32, rows exclusive to block
    }
    __syncthreads();
    #pragma unroll
    for (int r = 0; r < ROWS8; ++r) {
        int row = bin * ROWS8 + r;
        if (row >= krows) break;
        float* dst = W + (long long)row * out_f;
        const float* s = tile + r * out_f;
        if ((out_f & 3) == 0) {
            for (int c = tid * 4; c < out_f; c += 2048)
                *(float4*)&dst[c] = *(const float4*)&s[c];
        } else {
            for (int c = tid; c < out_f; c += 512) dst[c] = s[c];
        }
    }
}

// ---- Phase 3: GEMM partial[s] = A[:, slice] @ W[slice, o_tile], slice = 2 chunks of KS
__global__ __launch_bounds__(256) void smw_gemm4(
    const float* __restrict__ A, const float* __restrict__ W,
    float* __restrict__ partial, int in_features, int out_f, int krows, int Bsz) {
    __shared__ float As[64][KS + 4];
    __shared__ float Ws[KS][TILE_O];
    const int tid = threadIdx.x;
    const int tx = tid & 15;
    const int ty = tid >> 4;
    const int o_base = blockIdx.x * TILE_O;

    float acc[4][4] = {};
    #pragma unroll
    for (int half = 0; half < 2; ++half) {
        const int k0 = (blockIdx.y * 2 + half) * KS;
        __syncthreads();   // protect LDS reuse between halves (no-op cost on half 0)
        #pragma unroll
        for (int t = 0; t < 4; ++t) {
            int idx = t * 256 + tid;
            int b = idx >> 4;
            int c4 = (idx & 15) * 4;
            int gi = k0 + c4;
            float4 v = make_float4(0.f, 0.f, 0.f, 0.f);
            if (b < Bsz) {
                const float* src = A + (long long)b * in_features + gi;
                if (gi + 3 < krows) v = *(const float4*)src;
                else {
                    if (gi + 0 < krows) v.x = src[0];
                    if (gi + 1 < krows) v.y = src[1];
                    if (gi + 2 < krows) v.z = src[2];
                    if (gi + 3 < krows) v.w = src[3];
                }
            }
            *(float4*)&As[b][c4] = v;
        }
        #pragma unroll
        for (int t = 0; t < 4; ++t) {
            int idx = t * 256 + tid;
            int r = idx >> 4;
            int c4 = (idx & 15) * 4;
            int gi = k0 + r;
            int go = o_base + c4;
            float4 v = make_float4(0.f, 0.f, 0.f, 0.f);
            if (gi < krows) {
                const float* src = W + (long long)gi * out_f + go;
                if (go + 3 < out_f) v = *(const float4*)src;
                else {
                    if (go + 0 < out_f) v.x = src[0];
                    if (go + 1 < out_f) v.y = src[1];
                    if (go + 2 < out_f) v.z = src[2];
                    if (go + 3 < out_f) v.w = src[3];
                }
            }
            *(float4*)&Ws[r][c4] = v;
        }
        __syncthreads();

        #pragma unroll 8
        for (int i = 0; i < KS; ++i) {
            float4 w4 = *(const float4*)&Ws[i][tx * 4];
            float a[4];
            #pragma unroll
            for (int r = 0; r < 4; ++r) a[r] = As[ty * 4 + r][i];
            #pragma unroll
            for (int r = 0; r < 4; ++r) {
                acc[r][0] += a[r] * w4.x;
                acc[r][1] += a[r] * w4.y;
                acc[r][2] += a[r] * w4.z;
                acc[r][3] += a[r] * w4.w;
            }
        }
    }

    float* P = partial + (long long)blockIdx.y * 64 * PSTRIDE;
    #pragma unroll
    for (int r = 0; r < 4; ++r) {
        int b = ty * 4 + r;
        if (b < Bsz)
            *(float4*)&P[(long long)b * PSTRIDE + o_base + tx * 4] =
                make_float4(acc[r][0], acc[r][1], acc[r][2], acc[r][3]);
    }
}

// ---- Phase 4: out = bias + sum_s partial[s]  (float4 lanes; out_f % 4 == 0 gated)
__global__ void smw_reduce3(const float* __restrict__ partial,
                            const float* __restrict__ bias,
                            float* __restrict__ out, int out_f, int Bsz, int total4) {
    int idx = blockIdx.x * blockDim.x + threadIdx.x;
    if (idx >= total4) return;
    const int of4 = out_f >> 2;
    int b = idx / of4, o4 = idx - b * of4;
    const float4* B4 = (const float4*)bias;
    const float4* P4 = (const float4*)partial;
    float4 acc = B4[o4];
    #pragma unroll
    for (int s = 0; s < SLICES; ++s) {
        float4 v = P4[((long long)s * 64 + b) * (PSTRIDE >> 2) + o4];
        acc.x += v.x; acc.y += v.y; acc.z += v.z; acc.w += v.w;
    }
    ((float4*)out)[idx] = acc;
}

// ================= fallback path (round-1, known-good, needs only 16 MB ws) ==
__global__ void smw_build_fb(const int* __restrict__ mask, const float* __restrict__ wgt,
                             float* __restrict__ W, const int* __restrict__ flag,
                             int n_edges, int out_f) {
    int e = blockIdx.x * blockDim.x + threadIdx.x;
    if (e >= n_edges) return;
    int ci, co;
    if (*flag) {
        const long long* m64 = (const long long*)mask;
        ci = (int)m64[2 * (long long)e];
        co = (int)m64[2 * (long long)e + 1];
    } else {
        ci = mask[2 * e]; co = mask[2 * e + 1];
    }
    atomicAdd(&W[(long long)ci * out_f + co], wgt[e]);
}

__global__ void smw_init_out_fb(float* __restrict__ out, const float* __restrict__ bias,
                                int total, int out_f) {
    int idx = blockIdx.x * blockDim.x + threadIdx.x;
    if (idx < total) out[idx] = bias[idx % out_f];
}

__global__ __launch_bounds__(256) void smw_gemm_fb(
    const float* __restrict__ A, const float* __restrict__ W,
    float* __restrict__ out, int in_features, int out_f, int krows,
    int n_chunks, int Bsz) {
    __shared__ float As[64][36];
    __shared__ float Ws[32][64];
    const int tid = threadIdx.x;
    const int tx = tid & 15;
    const int ty = tid >> 4;
    const int o_base = blockIdx.x * 64;
    float acc[4][4] = {};
    for (int c = blockIdx.y; c < n_chunks; c += 8) {
        const int i0 = c * 32;
        __syncthreads();
        #pragma unroll
        for (int k = 0; k < 8; ++k) {
            int idx = k * 256 + tid;
            int i = idx & 31;
            int b = idx >> 5;
            float v = 0.0f;
            int gi = i0 + i;
            if (b < Bsz && gi < in_features) v = A[(long long)b * in_features + gi];
            As[b][i] = v;
        }
        #pragma unroll
        for (int k = 0; k < 8; ++k) {
            int idx = k * 256 + tid;
            int o = idx & 63;
            int i = idx >> 6;
            int gi = i0 + i;
            int go = o_base + o;
            Ws[i][o] = (gi < krows && go < out_f) ? W[(long long)gi * out_f + go] : 0.0f;
        }
        __syncthreads();
        #pragma unroll
        for (int i = 0; i < 32; ++i) {
            float4 w4 = *(const float4*)(&Ws[i][tx * 4]);
            float a[4];
            #pragma unroll
            for (int r = 0; r < 4; ++r) a[r] = As[ty * 4 + r][i];
            #pragma unroll
            for (int r = 0; r < 4; ++r) {
                acc[r][0] += a[r] * w4.x;
                acc[r][1] += a[r] * w4.y;
                acc[r][2] += a[r] * w4.z;
                acc[r][3] += a[r] * w4.w;
            }
        }
    }
    #pragma unroll
    for (int r = 0; r < 4; ++r) {
        int b = ty * 4 + r;
        if (b >= Bsz) continue;
        #pragma unroll
        for (int cc = 0; cc < 4; ++cc) {
            int o = o_base + tx * 4 + cc;
            if (o < out_f) atomicAdd(&out[(long long)b * out_f + o], acc[r][cc]);
        }
    }
}

// =============================================================================
static inline size_t align_up(size_t x, size_t a) { return (x + a - 1) & ~(a - 1); }

extern "C" void kernel_launch(void* const* d_in, const int* in_sizes, int n_in,
                              void* d_out, int out_size, void* d_ws, size_t ws_size,
                              hipStream_t stream) {
    const float* input = (const float*)d_in[0];
    const int*   mask  = (const int*)d_in[1];
    const float* wgt   = (const float*)d_in[2];
    const float* bias  = (const float*)d_in[3];
    float* out = (float*)d_out;

    const int out_f   = in_sizes[3];            // 2000
    const int n_edges = in_sizes[2];            // 2,000,000
    const int Bsz     = out_size / out_f;       // 64
    const int in_features = in_sizes[0] / Bsz;  // 20000
    const int krows   = out_f;                  // ci values < out_f per problem spec
    const int nbins   = (krows + ROWS8 - 1) / ROWS8;   // 250

    size_t W_bytes      = align_up((size_t)krows * out_f * 4, 1024);
    size_t binned_bytes = align_up((size_t)nbins * BIN_CAP8 * 8, 1024);   // 18.4 MB
    size_t part_bytes   = align_up((size_t)SLICES * 64 * PSTRIDE * 4, 1024);  // 8.4 MB
    size_t union_bytes  = binned_bytes > part_bytes ? binned_bytes : part_bytes;
    size_t cursor_bytes = (size_t)NB * CUR_STRIDE * 4;   // 32 KB padded cursors
    size_t meta_bytes   = cursor_bytes + 4096;
    size_t need_fast = W_bytes + union_bytes + meta_bytes;   // ~34.5 MB

    char* p = (char*)d_ws;
    float* W      = (float*)p;
    int2*  binned = (int2*)(p + W_bytes);         // dead after bin_build
    float* partial= (float*)(p + W_bytes);        // same region, used after
    int*   cursor = (int*)(p + W_bytes + union_bytes);
    int*   flag   = (int*)(p + W_bytes + union_bytes + cursor_bytes);

    const size_t lds_bytes = (size_t)ROWS8 * out_f * 4;   // <= 64 KB when out_f <= 2048
    const bool fast = (ws_size >= need_fast) && out_f <= 2048 && (out_f & 3) == 0 &&
                      krows <= 2048 && nbins <= NB && Bsz <= 64 && n_edges >= 1 &&
                      lds_bytes <= 65536 && (out_size & 3) == 0;

    if (fast) {
        hipMemsetAsync(cursor, 0, cursor_bytes, stream);
        smw_detect<<<1, 64, 0, stream>>>((const unsigned int*)mask, flag);
        int nseg = (n_edges + SEG4 - 1) / SEG4;                   // 245
        smw_scatter4<<<nseg, TPB_SC, 0, stream>>>(mask, wgt, flag, cursor, binned,
                                                  n_edges, krows, nbins);
        smw_bin_build3<<<nbins, 512, lds_bytes, stream>>>(binned, cursor, W, out_f, krows);
        dim3 grid((out_f + TILE_O - 1) / TILE_O, SLICES);         // 32 x 16
        smw_gemm4<<<grid, 256, 0, stream>>>(input, W, partial, in_features, out_f,
                                            krows, Bsz);
        int total4 = out_size >> 2;
        smw_reduce3<<<(total4 + 255) / 256, 256, 0, stream>>>(partial, bias, out,
                                                              out_f, Bsz, total4);
    } else {
        // round-1 known-good path (16 MB + flag)
        int* flag_fb = (int*)(p + (size_t)krows * out_f * 4);
        hipMemsetAsync(d_ws, 0, (size_t)krows * out_f * 4, stream);
        smw_detect<<<1, 64, 0, stream>>>((const unsigned int*)mask, flag_fb);
        smw_build_fb<<<(n_edges + 255) / 256, 256, 0, stream>>>(mask, wgt, W, flag_fb,
                                                                n_edges, out_f);
        smw_init_out_fb<<<(out_size + 255) / 256, 256, 0, stream>>>(out, bias, out_size, out_f);
        const int n_chunks = (krows + 31) / 32;
        dim3 grid((out_f + 63) / 64, 8);
        smw_gemm_fb<<<grid, 256, 0, stream>>>(input, W, out, in_features, out_f,
                                              krows, n_chunks, Bsz);
    }
}

// Round 7
// 66.520 us; speedup vs baseline: 1.1881x; 1.0301x over previous
//
#include <hip/hip_runtime.h>

// SparseMaskedLinear: out[b,co] = bias[co] + sum_e in[b,ci_e]*w_e  (B=64, dims 2000)
// Dense reformulation: W[ci][co] = sum w_e;  out = in[:, :2000] @ W + bias.
// Pipeline: detect -> scatter (LDS-staged, line-aligned coalesced flush) ->
//           bin_build (8-row LDS tiles, exclusive) -> gemm (2-chunk K) -> reduce.
// Round-7: scatter stages records per-bin in LDS and flushes 128B-coalesced,
// 64B-aligned runs (pads = zero-weight no-op records). Kills the 2M scattered
// 8B stores that showed 2.4x write amplification (round-3 WRITE_SIZE evidence).

#define ROWS8 8
#define NB 256                 // hist/stage slots (nbins <= 250 actual)
#define CUR_STRIDE 32          // one cursor per 128 B line
#define BIN_CAPB 10752         // per-bin cap: mean 8000 real + ~1760 pads + >5 sigma
#define E_PT 8
#define TPB_SC 512
#define SEG5 (TPB_SC * E_PT)   // 4096 edges per scatter block
#define SCAP 30                // staged records per bin per block (mean 16.4, 3.4 sigma)

#define TILE_O 64
#define KS 64
#define SLICES 16              // 16 partial slices, 2 K-chunks of 64 each
#define PSTRIDE 2048

// ---- int64-vs-int32 materialization detect (values < 2048 => int64 high words all 0)
__global__ void smw_detect(const unsigned int* __restrict__ m, int* __restrict__ flag) {
    if (blockIdx.x == 0 && threadIdx.x == 0) {
        unsigned int orv = 0u;
        for (int k = 0; k < 64; ++k) orv |= m[2 * k + 1];
        *flag = (orv == 0u) ? 1 : 0;   // 1 => int64 layout
    }
}

// ---- Phase 1: LDS-staged scatter. Load pass ranks via LDS atomic and stages
// the record in a per-bin LDS buffer. One padded (multiple-of-8 records = 64B)
// cursor reservation per (bin,block). Flush: 16-lane groups write each bin's
// run as contiguous, line-aligned stores; pad slots get {0, 0.0f} no-op records.
// Stage overflow (rare, ~3.4 sigma) falls back to direct scattered stores.
__global__ __launch_bounds__(512) void smw_scatter5(
    const int* __restrict__ mask, const float* __restrict__ wgt,
    const int* __restrict__ flag, int* __restrict__ cursor,
    int2* __restrict__ binned, int n_edges, int krows, int nbins) {
    __shared__ int hist[NB];
    __shared__ int sbase[NB];
    __shared__ int2 stage[NB * SCAP];          // 61,440 B
    const int tid = threadIdx.x;
    const long long e0 = (long long)blockIdx.x * SEG5;
    if (tid < NB) hist[tid] = 0;
    __syncthreads();
    const bool is64 = (*flag != 0);

    unsigned key[E_PT]; float wv[E_PT]; int pk[E_PT];  // overflow-only carry
    #pragma unroll
    for (int i = 0; i < E_PT; ++i) {
        long long e = e0 + (long long)i * TPB_SC + tid;
        pk[i] = -1; key[i] = 0u; wv[i] = 0.0f;
        if (e < n_edges) {
            int ci, co;
            if (is64) { int4 m = ((const int4*)mask)[e]; ci = m.x; co = m.z; }
            else      { int2 m = ((const int2*)mask)[e]; ci = m.x; co = m.y; }
            if ((unsigned)ci < (unsigned)krows) {
                int b = ci >> 3;                       // 8 rows per bin
                unsigned k = ((unsigned)(ci & 7) << 16) | (unsigned)(co & 0xFFFF);
                float w = wgt[e];
                int r = atomicAdd(&hist[b], 1);        // LDS rank
                if (r < SCAP) {
                    stage[b * SCAP + r] = make_int2((int)k, __float_as_int(w));
                } else {                               // rare overflow
                    pk[i] = (b << 16) | r;             // r < 4096
                    key[i] = k; wv[i] = w;
                }
            }
        }
    }
    __syncthreads();
    if (tid < nbins) {
        int c = hist[tid];
        int cp = (c + 7) & ~7;                         // 64B-aligned reservation
        sbase[tid] = cp ? atomicAdd(&cursor[tid * CUR_STRIDE], cp) : 0;
    }
    __syncthreads();
    // overflow direct writes (rare)
    #pragma unroll
    for (int i = 0; i < E_PT; ++i) {
        if (pk[i] >= 0) {
            int b = pk[i] >> 16, r = pk[i] & 0xFFFF;
            long long pos = (long long)sbase[b] + r;
            if (pos < BIN_CAPB)
                binned[(long long)b * BIN_CAPB + pos] =
                    make_int2((int)key[i], __float_as_int(wv[i]));
        }
    }
    // cooperative aligned flush: 16 lanes per bin, consecutive records
    const int grp = tid >> 4;                          // 32 groups
    const int ln  = tid & 15;
    for (int b = grp; b < nbins; b += 32) {
        int c  = hist[b];
        int cS = c < SCAP ? c : SCAP;
        int cp = (c + 7) & ~7;
        int bs = sbase[b];
        long long bb = (long long)b * BIN_CAPB;
        for (int k = ln; k < cp; k += 16) {
            if (bs + k >= BIN_CAPB) break;
            if (k < cS)
                binned[bb + bs + k] = stage[b * SCAP + k];
            else if (k >= c)
                binned[bb + bs + k] = make_int2(0, 0); // zero-weight no-op pad
            // cS <= k < c: overflow region, written above
        }
    }
}

// ---- Phase 2: per-bin exclusive build of 8 W-rows in dynamic LDS, plain stores.
__global__ __launch_bounds__(512) void smw_bin_build3(
    const int2* __restrict__ binned, const int* __restrict__ cursor,
    float* __restrict__ W, int out_f, int krows) {
    extern __shared__ float tile[];                 // ROWS8 * out_f floats (<= 64 KB)
    const int tid = threadIdx.x;
    const int bin = blockIdx.x;
    const int tile_elems = ROWS8 * out_f;
    if ((out_f & 3) == 0) {
        float4* t4 = (float4*)tile;
        int n4 = tile_elems >> 2;
        for (int t = tid; t < n4; t += 512) t4[t] = make_float4(0.f, 0.f, 0.f, 0.f);
    } else {
        for (int t = tid; t < tile_elems; t += 512) tile[t] = 0.0f;
    }
    __syncthreads();
    int n = cursor[bin * CUR_STRIDE];
    if (n > BIN_CAPB) n = BIN_CAPB;
    const int2* src = binned + (long long)bin * BIN_CAPB;
    for (int i = tid; i < n; i += 512) {
        int2 rec = src[i];
        unsigned k = (unsigned)rec.x;
        atomicAdd(&tile[(int)(k >> 16) * out_f + (int)(k & 0xFFFFu)],
                  __int_as_float(rec.y));           // ds_add_f32, rows exclusive
    }
    __syncthreads();
    #pragma unroll
    for (int r = 0; r < ROWS8; ++r) {
        int row = bin * ROWS8 + r;
        if (row >= krows) break;
        float* dst = W + (long long)row * out_f;
        const float* s = tile + r * out_f;
        if ((out_f & 3) == 0) {
            for (int c = tid * 4; c < out_f; c += 2048)
                *(float4*)&dst[c] = *(const float4*)&s[c];
        } else {
            for (int c = tid; c < out_f; c += 512) dst[c] = s[c];
        }
    }
}

// ---- Phase 3: GEMM partial[s] = A[:, slice] @ W[slice, o_tile], slice = 2 chunks of KS
__global__ __launch_bounds__(256) void smw_gemm4(
    const float* __restrict__ A, const float* __restrict__ W,
    float* __restrict__ partial, int in_features, int out_f, int krows, int Bsz) {
    __shared__ float As[64][KS + 4];
    __shared__ float Ws[KS][TILE_O];
    const int tid = threadIdx.x;
    const int tx = tid & 15;
    const int ty = tid >> 4;
    const int o_base = blockIdx.x * TILE_O;

    float acc[4][4] = {};
    #pragma unroll
    for (int half = 0; half < 2; ++half) {
        const int k0 = (blockIdx.y * 2 + half) * KS;
        __syncthreads();
        #pragma unroll
        for (int t = 0; t < 4; ++t) {
            int idx = t * 256 + tid;
            int b = idx >> 4;
            int c4 = (idx & 15) * 4;
            int gi = k0 + c4;
            float4 v = make_float4(0.f, 0.f, 0.f, 0.f);
            if (b < Bsz) {
                const float* src = A + (long long)b * in_features + gi;
                if (gi + 3 < krows) v = *(const float4*)src;
                else {
                    if (gi + 0 < krows) v.x = src[0];
                    if (gi + 1 < krows) v.y = src[1];
                    if (gi + 2 < krows) v.z = src[2];
                    if (gi + 3 < krows) v.w = src[3];
                }
            }
            *(float4*)&As[b][c4] = v;
        }
        #pragma unroll
        for (int t = 0; t < 4; ++t) {
            int idx = t * 256 + tid;
            int r = idx >> 4;
            int c4 = (idx & 15) * 4;
            int gi = k0 + r;
            int go = o_base + c4;
            float4 v = make_float4(0.f, 0.f, 0.f, 0.f);
            if (gi < krows) {
                const float* src = W + (long long)gi * out_f + go;
                if (go + 3 < out_f) v = *(const float4*)src;
                else {
                    if (go + 0 < out_f) v.x = src[0];
                    if (go + 1 < out_f) v.y = src[1];
                    if (go + 2 < out_f) v.z = src[2];
                    if (go + 3 < out_f) v.w = src[3];
                }
            }
            *(float4*)&Ws[r][c4] = v;
        }
        __syncthreads();

        #pragma unroll 8
        for (int i = 0; i < KS; ++i) {
            float4 w4 = *(const float4*)&Ws[i][tx * 4];
            float a[4];
            #pragma unroll
            for (int r = 0; r < 4; ++r) a[r] = As[ty * 4 + r][i];
            #pragma unroll
            for (int r = 0; r < 4; ++r) {
                acc[r][0] += a[r] * w4.x;
                acc[r][1] += a[r] * w4.y;
                acc[r][2] += a[r] * w4.z;
                acc[r][3] += a[r] * w4.w;
            }
        }
    }

    float* P = partial + (long long)blockIdx.y * 64 * PSTRIDE;
    #pragma unroll
    for (int r = 0; r < 4; ++r) {
        int b = ty * 4 + r;
        if (b < Bsz)
            *(float4*)&P[(long long)b * PSTRIDE + o_base + tx * 4] =
                make_float4(acc[r][0], acc[r][1], acc[r][2], acc[r][3]);
    }
}

// ---- Phase 4: out = bias + sum_s partial[s]  (float4 lanes; out_f % 4 == 0 gated)
__global__ void smw_reduce3(const float* __restrict__ partial,
                            const float* __restrict__ bias,
                            float* __restrict__ out, int out_f, int Bsz, int total4) {
    int idx = blockIdx.x * blockDim.x + threadIdx.x;
    if (idx >= total4) return;
    const int of4 = out_f >> 2;
    int b = idx / of4, o4 = idx - b * of4;
    const float4* B4 = (const float4*)bias;
    const float4* P4 = (const float4*)partial;
    float4 acc = B4[o4];
    #pragma unroll
    for (int s = 0; s < SLICES; ++s) {
        float4 v = P4[((long long)s * 64 + b) * (PSTRIDE >> 2) + o4];
        acc.x += v.x; acc.y += v.y; acc.z += v.z; acc.w += v.w;
    }
    ((float4*)out)[idx] = acc;
}

// ================= fallback path (round-1, known-good, needs only 16 MB ws) ==
__global__ void smw_build_fb(const int* __restrict__ mask, const float* __restrict__ wgt,
                             float* __restrict__ W, const int* __restrict__ flag,
                             int n_edges, int out_f) {
    int e = blockIdx.x * blockDim.x + threadIdx.x;
    if (e >= n_edges) return;
    int ci, co;
    if (*flag) {
        const long long* m64 = (const long long*)mask;
        ci = (int)m64[2 * (long long)e];
        co = (int)m64[2 * (long long)e + 1];
    } else {
        ci = mask[2 * e]; co = mask[2 * e + 1];
    }
    atomicAdd(&W[(long long)ci * out_f + co], wgt[e]);
}

__global__ void smw_init_out_fb(float* __restrict__ out, const float* __restrict__ bias,
                                int total, int out_f) {
    int idx = blockIdx.x * blockDim.x + threadIdx.x;
    if (idx < total) out[idx] = bias[idx % out_f];
}

__global__ __launch_bounds__(256) void smw_gemm_fb(
    const float* __restrict__ A, const float* __restrict__ W,
    float* __restrict__ out, int in_features, int out_f, int krows,
    int n_chunks, int Bsz) {
    __shared__ float As[64][36];
    __shared__ float Ws[32][64];
    const int tid = threadIdx.x;
    const int tx = tid & 15;
    const int ty = tid >> 4;
    const int o_base = blockIdx.x * 64;
    float acc[4][4] = {};
    for (int c = blockIdx.y; c < n_chunks; c += 8) {
        const int i0 = c * 32;
        __syncthreads();
        #pragma unroll
        for (int k = 0; k < 8; ++k) {
            int idx = k * 256 + tid;
            int i = idx & 31;
            int b = idx >> 5;
            float v = 0.0f;
            int gi = i0 + i;
            if (b < Bsz && gi < in_features) v = A[(long long)b * in_features + gi];
            As[b][i] = v;
        }
        #pragma unroll
        for (int k = 0; k < 8; ++k) {
            int idx = k * 256 + tid;
            int o = idx & 63;
            int i = idx >> 6;
            int gi = i0 + i;
            int go = o_base + o;
            Ws[i][o] = (gi < krows && go < out_f) ? W[(long long)gi * out_f + go] : 0.0f;
        }
        __syncthreads();
        #pragma unroll
        for (int i = 0; i < 32; ++i) {
            float4 w4 = *(const float4*)(&Ws[i][tx * 4]);
            float a[4];
            #pragma unroll
            for (int r = 0; r < 4; ++r) a[r] = As[ty * 4 + r][i];
            #pragma unroll
            for (int r = 0; r < 4; ++r) {
                acc[r][0] += a[r] * w4.x;
                acc[r][1] += a[r] * w4.y;
                acc[r][2] += a[r] * w4.z;
                acc[r][3] += a[r] * w4.w;
            }
        }
    }
    #pragma unroll
    for (int r = 0; r < 4; ++r) {
        int b = ty * 4 + r;
        if (b >= Bsz) continue;
        #pragma unroll
        for (int cc = 0; cc < 4; ++cc) {
            int o = o_base + tx * 4 + cc;
            if (o < out_f) atomicAdd(&out[(long long)b * out_f + o], acc[r][cc]);
        }
    }
}

// =============================================================================
static inline size_t align_up(size_t x, size_t a) { return (x + a - 1) & ~(a - 1); }

extern "C" void kernel_launch(void* const* d_in, const int* in_sizes, int n_in,
                              void* d_out, int out_size, void* d_ws, size_t ws_size,
                              hipStream_t stream) {
    const float* input = (const float*)d_in[0];
    const int*   mask  = (const int*)d_in[1];
    const float* wgt   = (const float*)d_in[2];
    const float* bias  = (const float*)d_in[3];
    float* out = (float*)d_out;

    const int out_f   = in_sizes[3];            // 2000
    const int n_edges = in_sizes[2];            // 2,000,000
    const int Bsz     = out_size / out_f;       // 64
    const int in_features = in_sizes[0] / Bsz;  // 20000
    const int krows   = out_f;                  // ci values < out_f per problem spec
    const int nbins   = (krows + ROWS8 - 1) / ROWS8;   // 250

    size_t W_bytes      = align_up((size_t)krows * out_f * 4, 1024);
    size_t binned_bytes = align_up((size_t)nbins * BIN_CAPB * 8, 1024);   // 21.5 MB
    size_t part_bytes   = align_up((size_t)SLICES * 64 * PSTRIDE * 4, 1024);  // 8.4 MB
    size_t union_bytes  = binned_bytes > part_bytes ? binned_bytes : part_bytes;
    size_t cursor_bytes = (size_t)NB * CUR_STRIDE * 4;   // 32 KB padded cursors
    size_t meta_bytes   = cursor_bytes + 4096;
    size_t need_fast = W_bytes + union_bytes + meta_bytes;   // ~37.6 MB

    char* p = (char*)d_ws;
    float* W      = (float*)p;
    int2*  binned = (int2*)(p + W_bytes);         // dead after bin_build
    float* partial= (float*)(p + W_bytes);        // same region, used after
    int*   cursor = (int*)(p + W_bytes + union_bytes);
    int*   flag   = (int*)(p + W_bytes + union_bytes + cursor_bytes);

    const size_t lds_bytes = (size_t)ROWS8 * out_f * 4;   // <= 64 KB when out_f <= 2048
    const bool fast = (ws_size >= need_fast) && out_f <= 2048 && (out_f & 3) == 0 &&
                      krows <= 2048 && nbins <= NB && Bsz <= 64 && n_edges >= 1 &&
                      lds_bytes <= 65536 && (out_size & 3) == 0;

    if (fast) {
        hipMemsetAsync(cursor, 0, cursor_bytes, stream);
        smw_detect<<<1, 64, 0, stream>>>((const unsigned int*)mask, flag);
        int nseg = (n_edges + SEG5 - 1) / SEG5;                   // 489
        smw_scatter5<<<nseg, TPB_SC, 0, stream>>>(mask, wgt, flag, cursor, binned,
                                                  n_edges, krows, nbins);
        smw_bin_build3<<<nbins, 512, lds_bytes, stream>>>(binned, cursor, W, out_f, krows);
        dim3 grid((out_f + TILE_O - 1) / TILE_O, SLICES);         // 32 x 16
        smw_gemm4<<<grid, 256, 0, stream>>>(input, W, partial, in_features, out_f,
                                            krows, Bsz);
        int total4 = out_size >> 2;
        smw_reduce3<<<(total4 + 255) / 256, 256, 0, stream>>>(partial, bias, out,
                                                              out_f, Bsz, total4);
    } else {
        // round-1 known-good path (16 MB + flag)
        int* flag_fb = (int*)(p + (size_t)krows * out_f * 4);
        hipMemsetAsync(d_ws, 0, (size_t)krows * out_f * 4, stream);
        smw_detect<<<1, 64, 0, stream>>>((const unsigned int*)mask, flag_fb);
        smw_build_fb<<<(n_edges + 255) / 256, 256, 0, stream>>>(mask, wgt, W, flag_fb,
                                                                n_edges, out_f);
        smw_init_out_fb<<<(out_size + 255) / 256, 256, 0, stream>>>(out, bias, out_size, out_f);
        const int n_chunks = (krows + 31) / 32;
        dim3 grid((out_f + 63) / 64, 8);
        smw_gemm_fb<<<grid, 256, 0, stream>>>(input, W, out, in_features, out_f,
                                              krows, n_chunks, Bsz);
    }
}